// Round 1
// baseline (237.863 us; speedup 1.0000x reference)
//
#include <hip/hip_runtime.h>
#include <hip/hip_bf16.h>

// B=64, T=1024, H=512, M=256
// outputs: h_new (64x512) | ctx (64x512) | align (64x1024), all fp32

typedef __attribute__((ext_vector_type(8))) __bf16 bf16x8;
typedef __attribute__((ext_vector_type(8))) unsigned short u16x8;
typedef __attribute__((ext_vector_type(4))) float f32x4;

__device__ __forceinline__ unsigned short f2bf(float f) {
    __hip_bfloat16 h = __float2bfloat16(f);
    return __builtin_bit_cast(unsigned short, h);
}
__device__ __forceinline__ float tanh_fast(float x) {
    float e = __expf(2.0f * x);
    return 1.0f - 2.0f / (e + 1.0f);   // safe at +/-inf
}
__device__ __forceinline__ float sigmoid_f(float x) {
    return 1.0f / (1.0f + __expf(-x));
}

// ---------------- small fp32 GEMM body: out[64 x N] tile at col c0 ----------
// out[m,n] = sum_k x[m,k]*W[n,k] + bias1[n] (+ bias2[n])
// x[m,k] = k<w1 ? A1[m*w1+k] : A2[m*(K-w1)+(k-w1)]
__device__ __forceinline__ void gemm64_body(
    float (*As)[65], float (*Bs)[65],
    const float* __restrict__ A1, int w1, const float* __restrict__ A2, int K,
    const float* __restrict__ W, const float* __restrict__ bias1,
    const float* __restrict__ bias2, int has_b2,
    float* __restrict__ out, int N, int c0)
{
    const int tx = threadIdx.x, ty = threadIdx.y;
    const int tid = ty * 16 + tx;
    const int m_ = tid >> 2, q = tid & 3;
    const int w2 = K - w1;
    float acc[4][4] = {{0.f}};
    for (int k0 = 0; k0 < K; k0 += 16) {
        __syncthreads();
#pragma unroll
        for (int j = 0; j < 4; ++j) {
            int k = k0 + q * 4 + j;
            float val;
            if (k < w1) val = A1[m_ * w1 + k];
            else        val = A2[m_ * w2 + (k - w1)];
            As[q * 4 + j][m_] = val;
        }
        {
            const float4 wv = *(const float4*)&W[(size_t)(c0 + m_) * K + k0 + q * 4];
            Bs[q * 4 + 0][m_] = wv.x;
            Bs[q * 4 + 1][m_] = wv.y;
            Bs[q * 4 + 2][m_] = wv.z;
            Bs[q * 4 + 3][m_] = wv.w;
        }
        __syncthreads();
#pragma unroll
        for (int kk = 0; kk < 16; ++kk) {
            float a[4], b[4];
#pragma unroll
            for (int i = 0; i < 4; ++i) a[i] = As[kk][ty * 4 + i];
#pragma unroll
            for (int j = 0; j < 4; ++j) b[j] = Bs[kk][tx * 4 + j];
#pragma unroll
            for (int i = 0; i < 4; ++i)
#pragma unroll
                for (int j = 0; j < 4; ++j) acc[i][j] += a[i] * b[j];
        }
    }
#pragma unroll
    for (int i = 0; i < 4; ++i) {
        int m = ty * 4 + i;
#pragma unroll
        for (int j = 0; j < 4; ++j) {
            int n = c0 + tx * 4 + j;
            float r = acc[i][j] + bias1[n];
            if (has_b2) r += bias2[n];
            out[(size_t)m * N + n] = r;
        }
    }
}

// gi = x@W_ih^T+b_ih  (y=0),  gh = h@W_hh^T+b_hh  (y=1)
__global__ __launch_bounds__(256) void gru_gemm_kernel(
    const float* __restrict__ memory, const float* __restrict__ context,
    const float* __restrict__ rnn_state,
    const float* __restrict__ W_ih, const float* __restrict__ b_ih,
    const float* __restrict__ W_hh, const float* __restrict__ b_hh,
    float* __restrict__ gi, float* __restrict__ gh)
{
    __shared__ float As[16][65];
    __shared__ float Bs[16][65];
    const int c0 = blockIdx.x * 64;
    if (blockIdx.y == 0)
        gemm64_body(As, Bs, memory, 256, context, 768, W_ih, b_ih, b_ih, 0, gi, 1536, c0);
    else
        gemm64_body(As, Bs, rnn_state, 512, rnn_state, 512, W_hh, b_hh, b_hh, 0, gh, 1536, c0);
}

// q = h_new@Wq^T + bq + ba
__global__ __launch_bounds__(256) void pq_gemm_kernel(
    const float* __restrict__ h_new, const float* __restrict__ Wq,
    const float* __restrict__ bq, const float* __restrict__ ba,
    float* __restrict__ q)
{
    __shared__ float As[16][65];
    __shared__ float Bs[16][65];
    gemm64_body(As, Bs, h_new, 512, h_new, 512, Wq, bq, ba, 1, q, 512, blockIdx.x * 64);
}

__global__ __launch_bounds__(256) void gru_elem_kernel(
    const float* __restrict__ gi, const float* __restrict__ gh,
    const float* __restrict__ h0, float* __restrict__ hnew)
{
    int idx = blockIdx.x * 256 + threadIdx.x;      // < 32768
    int b = idx >> 9, h = idx & 511;
    size_t base = (size_t)b * 1536;
    float ir = gi[base + h], iz = gi[base + 512 + h], inn = gi[base + 1024 + h];
    float hr = gh[base + h], hz = gh[base + 512 + h], hn = gh[base + 1024 + h];
    float r = sigmoid_f(ir + hr);
    float z = sigmoid_f(iz + hz);
    float n = tanh_fast(inn + r * hn);
    hnew[idx] = (1.f - z) * n + z * h0[idx];
}

__global__ __launch_bounds__(256) void waconv_kernel(
    const float* __restrict__ Wa, unsigned short* __restrict__ WaB)
{
    int i = (blockIdx.x * 256 + threadIdx.x) * 4;  // 262144 total
    float4 f = *(const float4*)&Wa[i];
    WaB[i + 0] = f2bf(f.x);
    WaB[i + 1] = f2bf(f.y);
    WaB[i + 2] = f2bf(f.z);
    WaB[i + 3] = f2bf(f.w);
}

// ---------------- fused scores kernel -------------------------------------
// block = 256 thr (4 waves) handles 64 annotation rows x all 512 cols.
// scores[r] = sum_j v[j]*tanh(q[b,j] + sum_k ann[r,k]*Wa[j,k])
__global__ __launch_bounds__(256) void scores_kernel(
    const float* __restrict__ ann, const unsigned short* __restrict__ WaB,
    const float* __restrict__ qv, const float* __restrict__ v,
    float* __restrict__ scores)
{
    __shared__ unsigned short Asb[64 * 40];   // 64 rows x 32 bf16, stride 40 (+16B pad)
    __shared__ unsigned short Bsb[512 * 40];  // 512 n-rows x 32 bf16
    __shared__ float s_sc[64];
    const int tid = threadIdx.x;
    const int lane = tid & 63;
    const int w = tid >> 6;                   // wave 0..3 -> cols w*128..
    const int r0 = blockIdx.x * 64;
    const int b = r0 >> 10;
    if (tid < 64) s_sc[tid] = 0.f;

    f32x4 acc[4][8];
#pragma unroll
    for (int i = 0; i < 4; ++i)
#pragma unroll
        for (int j = 0; j < 8; ++j) acc[i][j] = (f32x4){0.f, 0.f, 0.f, 0.f};

    const int arow = tid >> 2;                // 0..63
    const int aq = tid & 3;                   // 8 floats each

    for (int kt = 0; kt < 16; ++kt) {         // K=512, BK=32
        __syncthreads();
        {   // A: fp32 -> bf16 reg-stage
            const float* src = ann + (size_t)(r0 + arow) * 512 + kt * 32 + aq * 8;
            float4 f0 = *(const float4*)src;
            float4 f1 = *(const float4*)(src + 4);
            u16x8 p;
            p[0] = f2bf(f0.x); p[1] = f2bf(f0.y); p[2] = f2bf(f0.z); p[3] = f2bf(f0.w);
            p[4] = f2bf(f1.x); p[5] = f2bf(f1.y); p[6] = f2bf(f1.z); p[7] = f2bf(f1.w);
            *(u16x8*)&Asb[arow * 40 + aq * 8] = p;
        }
#pragma unroll
        for (int c = 0; c < 8; ++c) {         // B: already bf16
            int chunk = tid + c * 256;        // 0..2047
            int n = chunk >> 2, q = chunk & 3;
            u16x8 wv = *(const u16x8*)&WaB[(size_t)n * 512 + kt * 32 + q * 8];
            *(u16x8*)&Bsb[n * 40 + q * 8] = wv;
        }
        __syncthreads();
        bf16x8 af[4];
#pragma unroll
        for (int tr = 0; tr < 4; ++tr) {
            int row = tr * 16 + (lane & 15);
            af[tr] = __builtin_bit_cast(bf16x8, *(const u16x8*)&Asb[row * 40 + (lane >> 4) * 8]);
        }
#pragma unroll
        for (int tc = 0; tc < 8; ++tc) {
            int n = w * 128 + tc * 16 + (lane & 15);
            bf16x8 bf = __builtin_bit_cast(bf16x8, *(const u16x8*)&Bsb[n * 40 + (lane >> 4) * 8]);
#pragma unroll
            for (int tr = 0; tr < 4; ++tr)
                acc[tr][tc] = __builtin_amdgcn_mfma_f32_16x16x32_bf16(af[tr], bf, acc[tr][tc], 0, 0, 0);
        }
    }

    // epilogue: rowsum of tanh(acc+q)*v
    float rsum[4][4];
#pragma unroll
    for (int i = 0; i < 4; ++i)
#pragma unroll
        for (int j = 0; j < 4; ++j) rsum[i][j] = 0.f;

#pragma unroll
    for (int tc = 0; tc < 8; ++tc) {
        int col = w * 128 + tc * 16 + (lane & 15);
        float qq = qv[b * 512 + col];
        float vv = v[col];
#pragma unroll
        for (int tr = 0; tr < 4; ++tr) {
            f32x4 a = acc[tr][tc];
#pragma unroll
            for (int r2 = 0; r2 < 4; ++r2)
                rsum[tr][r2] += tanh_fast(a[r2] + qq) * vv;
        }
    }
#pragma unroll
    for (int m = 1; m < 16; m <<= 1) {
#pragma unroll
        for (int tr = 0; tr < 4; ++tr)
#pragma unroll
            for (int r2 = 0; r2 < 4; ++r2)
                rsum[tr][r2] += __shfl_xor(rsum[tr][r2], m, 64);
    }
    if ((lane & 15) == 0) {
        int g = lane >> 4;
#pragma unroll
        for (int tr = 0; tr < 4; ++tr)
#pragma unroll
            for (int r2 = 0; r2 < 4; ++r2)
                atomicAdd(&s_sc[tr * 16 + g * 4 + r2], rsum[tr][r2]);
    }
    __syncthreads();
    if (tid < 64) scores[r0 + tid] = s_sc[tid];
}

__global__ __launch_bounds__(256) void softmax_kernel(
    const float* __restrict__ scores, float* __restrict__ align_)
{
    const int b = blockIdx.x, tid = threadIdx.x;
    __shared__ float red[256];
    float s[4];
#pragma unroll
    for (int j = 0; j < 4; ++j) s[j] = scores[b * 1024 + j * 256 + tid];
    float mx = fmaxf(fmaxf(s[0], s[1]), fmaxf(s[2], s[3]));
    red[tid] = mx; __syncthreads();
    for (int off = 128; off > 0; off >>= 1) {
        if (tid < off) red[tid] = fmaxf(red[tid], red[tid + off]);
        __syncthreads();
    }
    mx = red[0]; __syncthreads();
    float e[4], sum = 0.f;
#pragma unroll
    for (int j = 0; j < 4; ++j) { e[j] = __expf(s[j] - mx); sum += e[j]; }
    red[tid] = sum; __syncthreads();
    for (int off = 128; off > 0; off >>= 1) {
        if (tid < off) red[tid] += red[tid + off];
        __syncthreads();
    }
    float inv = 1.0f / red[0];
#pragma unroll
    for (int j = 0; j < 4; ++j) align_[b * 1024 + j * 256 + tid] = e[j] * inv;
}

__global__ __launch_bounds__(256) void ctx_part_kernel(
    const float* __restrict__ ann, const float* __restrict__ align_,
    float* __restrict__ part)
{
    const int tid = threadIdx.x;
    const int b = blockIdx.y;
    const int d = blockIdx.x * 256 + tid;
    const int tc = blockIdx.z;
    __shared__ float al[256];
    al[tid] = align_[b * 1024 + tc * 256 + tid];
    __syncthreads();
    const float* ap = ann + ((size_t)(b * 1024 + tc * 256)) * 512 + d;
    float acc = 0.f;
#pragma unroll 4
    for (int tt = 0; tt < 256; ++tt) acc += al[tt] * ap[(size_t)tt * 512];
    part[(size_t)(tc * 64 + b) * 512 + d] = acc;
}

__global__ __launch_bounds__(256) void ctx_reduce_kernel(
    const float* __restrict__ part, float* __restrict__ ctx)
{
    int idx = blockIdx.x * 256 + threadIdx.x;  // < 32768
    ctx[idx] = part[idx] + part[32768 + idx] + part[65536 + idx] + part[98304 + idx];
}

extern "C" void kernel_launch(void* const* d_in, const int* in_sizes, int n_in,
                              void* d_out, int out_size, void* d_ws, size_t ws_size,
                              hipStream_t stream)
{
    (void)in_sizes; (void)n_in; (void)out_size; (void)ws_size;
    const float* memory    = (const float*)d_in[0];
    const float* context   = (const float*)d_in[1];
    const float* rnn_state = (const float*)d_in[2];
    const float* ann       = (const float*)d_in[3];
    const float* W_ih      = (const float*)d_in[4];
    const float* b_ih      = (const float*)d_in[5];
    const float* W_hh      = (const float*)d_in[6];
    const float* b_hh      = (const float*)d_in[7];
    const float* Wq        = (const float*)d_in[8];
    const float* bq        = (const float*)d_in[9];
    const float* Wa        = (const float*)d_in[10];
    const float* ba        = (const float*)d_in[11];
    const float* v         = (const float*)d_in[12];

    float* out    = (float*)d_out;
    float* h_new  = out;               // 32768
    float* ctx    = out + 32768;       // 32768
    float* align_ = out + 65536;       // 65536

    float* ws   = (float*)d_ws;
    float* gi   = ws;                  // 98304
    float* gh   = ws + 98304;          // 98304
    float* q    = ws + 196608;         // 32768
    float* sc   = ws + 229376;         // 65536
    float* part = ws + 294912;         // 131072
    unsigned short* WaB = (unsigned short*)((char*)d_ws + 1703936); // 512KB

    gru_gemm_kernel<<<dim3(24, 2), dim3(16, 16), 0, stream>>>(
        memory, context, rnn_state, W_ih, b_ih, W_hh, b_hh, gi, gh);
    waconv_kernel<<<dim3(256), dim3(256), 0, stream>>>(Wa, WaB);
    gru_elem_kernel<<<dim3(128), dim3(256), 0, stream>>>(gi, gh, rnn_state, h_new);
    pq_gemm_kernel<<<dim3(8), dim3(16, 16), 0, stream>>>(h_new, Wq, bq, ba, q);
    scores_kernel<<<dim3(1024), dim3(256), 0, stream>>>(ann, WaB, q, v, sc);
    softmax_kernel<<<dim3(64), dim3(256), 0, stream>>>(sc, align_);
    ctx_part_kernel<<<dim3(2, 64, 4), dim3(256), 0, stream>>>(ann, align_, part);
    ctx_reduce_kernel<<<dim3(128), dim3(256), 0, stream>>>(part, ctx);
}

// Round 2
// 205.845 us; speedup vs baseline: 1.1555x; 1.1555x over previous
//
#include <hip/hip_runtime.h>
#include <hip/hip_bf16.h>

// B=64, T=1024, H=512, M=256
// outputs: h_new (64x512) | ctx (64x512) | align (64x1024), all fp32

typedef __attribute__((ext_vector_type(8))) __bf16 bf16x8;
typedef __attribute__((ext_vector_type(8))) unsigned short u16x8;
typedef __attribute__((ext_vector_type(4))) float f32x4;

__device__ __forceinline__ unsigned short f2bf(float f) {
    __hip_bfloat16 h = __float2bfloat16(f);
    return __builtin_bit_cast(unsigned short, h);
}
__device__ __forceinline__ float tanh_fast(float x) {
    float e = __expf(2.0f * x);
    return 1.0f - 2.0f / (e + 1.0f);   // safe at +/-inf
}
__device__ __forceinline__ float sigmoid_f(float x) {
    return 1.0f / (1.0f + __expf(-x));
}

// ---------------- small fp32 GEMM body (unchanged) --------------------------
__device__ __forceinline__ void gemm64_body(
    float (*As)[65], float (*Bs)[65],
    const float* __restrict__ A1, int w1, const float* __restrict__ A2, int K,
    const float* __restrict__ W, const float* __restrict__ bias1,
    const float* __restrict__ bias2, int has_b2,
    float* __restrict__ out, int N, int c0)
{
    const int tx = threadIdx.x, ty = threadIdx.y;
    const int tid = ty * 16 + tx;
    const int m_ = tid >> 2, q = tid & 3;
    const int w2 = K - w1;
    float acc[4][4] = {{0.f}};
    for (int k0 = 0; k0 < K; k0 += 16) {
        __syncthreads();
#pragma unroll
        for (int j = 0; j < 4; ++j) {
            int k = k0 + q * 4 + j;
            float val;
            if (k < w1) val = A1[m_ * w1 + k];
            else        val = A2[m_ * w2 + (k - w1)];
            As[q * 4 + j][m_] = val;
        }
        {
            const float4 wv = *(const float4*)&W[(size_t)(c0 + m_) * K + k0 + q * 4];
            Bs[q * 4 + 0][m_] = wv.x;
            Bs[q * 4 + 1][m_] = wv.y;
            Bs[q * 4 + 2][m_] = wv.z;
            Bs[q * 4 + 3][m_] = wv.w;
        }
        __syncthreads();
#pragma unroll
        for (int kk = 0; kk < 16; ++kk) {
            float a[4], b[4];
#pragma unroll
            for (int i = 0; i < 4; ++i) a[i] = As[kk][ty * 4 + i];
#pragma unroll
            for (int j = 0; j < 4; ++j) b[j] = Bs[kk][tx * 4 + j];
#pragma unroll
            for (int i = 0; i < 4; ++i)
#pragma unroll
                for (int j = 0; j < 4; ++j) acc[i][j] += a[i] * b[j];
        }
    }
#pragma unroll
    for (int i = 0; i < 4; ++i) {
        int m = ty * 4 + i;
#pragma unroll
        for (int j = 0; j < 4; ++j) {
            int n = c0 + tx * 4 + j;
            float r = acc[i][j] + bias1[n];
            if (has_b2) r += bias2[n];
            out[(size_t)m * N + n] = r;
        }
    }
}

__global__ __launch_bounds__(256) void gru_gemm_kernel(
    const float* __restrict__ memory, const float* __restrict__ context,
    const float* __restrict__ rnn_state,
    const float* __restrict__ W_ih, const float* __restrict__ b_ih,
    const float* __restrict__ W_hh, const float* __restrict__ b_hh,
    float* __restrict__ gi, float* __restrict__ gh)
{
    __shared__ float As[16][65];
    __shared__ float Bs[16][65];
    const int c0 = blockIdx.x * 64;
    if (blockIdx.y == 0)
        gemm64_body(As, Bs, memory, 256, context, 768, W_ih, b_ih, b_ih, 0, gi, 1536, c0);
    else
        gemm64_body(As, Bs, rnn_state, 512, rnn_state, 512, W_hh, b_hh, b_hh, 0, gh, 1536, c0);
}

__global__ __launch_bounds__(256) void pq_gemm_kernel(
    const float* __restrict__ h_new, const float* __restrict__ Wq,
    const float* __restrict__ bq, const float* __restrict__ ba,
    float* __restrict__ q)
{
    __shared__ float As[16][65];
    __shared__ float Bs[16][65];
    gemm64_body(As, Bs, h_new, 512, h_new, 512, Wq, bq, ba, 1, q, 512, blockIdx.x * 64);
}

__global__ __launch_bounds__(256) void gru_elem_kernel(
    const float* __restrict__ gi, const float* __restrict__ gh,
    const float* __restrict__ h0, float* __restrict__ hnew)
{
    int idx = blockIdx.x * 256 + threadIdx.x;      // < 32768
    int b = idx >> 9, h = idx & 511;
    size_t base = (size_t)b * 1536;
    float ir = gi[base + h], iz = gi[base + 512 + h], inn = gi[base + 1024 + h];
    float hr = gh[base + h], hz = gh[base + 512 + h], hn = gh[base + 1024 + h];
    float r = sigmoid_f(ir + hr);
    float z = sigmoid_f(iz + hz);
    float n = tanh_fast(inn + r * hn);
    hnew[idx] = (1.f - z) * n + z * h0[idx];
}

// Wa fp32 [512][512] -> fragment-major bf16:
// chunk cb = NB*16 + kt (NB: 16-col block of n, kt: 32-wide k tile)
// WaB[cb*512 + l*8 + e] = bf16( Wa[NB*16 + (l&15)][kt*32 + (l>>4)*8 + e] )
__global__ __launch_bounds__(256) void waconv_kernel(
    const float* __restrict__ Wa, unsigned short* __restrict__ WaB)
{
    const int t = threadIdx.x;
    const int cb = blockIdx.x * 4 + (t >> 6);      // 0..511
    const int l = t & 63;
    const int NB = cb >> 4, kt = cb & 15;
    const float* src = Wa + (size_t)(NB * 16 + (l & 15)) * 512 + kt * 32 + (l >> 4) * 8;
    float4 f0 = *(const float4*)src;
    float4 f1 = *(const float4*)(src + 4);
    u16x8 p;
    p[0] = f2bf(f0.x); p[1] = f2bf(f0.y); p[2] = f2bf(f0.z); p[3] = f2bf(f0.w);
    p[4] = f2bf(f1.x); p[5] = f2bf(f1.y); p[6] = f2bf(f1.z); p[7] = f2bf(f1.w);
    *(u16x8*)&WaB[(size_t)cb * 512 + l * 8] = p;
}

// ---------------- fused scores kernel v2 ------------------------------------
// 512 thr (8 waves: 2 wave-rows x 4 wave-cols), 128 ann rows x 512 cols/block.
// Double-buffered LDS, fragment-major layouts, B via global_load_lds.
__global__ __launch_bounds__(512, 2) void scores_kernel(
    const float* __restrict__ ann, const unsigned short* __restrict__ WaB,
    const float* __restrict__ qv, const float* __restrict__ v,
    float* __restrict__ scores)
{
    __shared__ unsigned short As[2][4096];    // 8 KB each: 8 RB chunks x 64 lanes x 8
    __shared__ unsigned short Bs[2][16384];   // 32 KB each: 32 NB chunks x 64 lanes x 8
    __shared__ float s_sc[128];

    const int tid = threadIdx.x;
    const int l = tid & 63;
    const int w = tid >> 6;          // 0..7
    const int wr = w >> 2;           // wave-row 0..1  (rows wr*64..+64)
    const int wc = w & 3;            // wave-col 0..3  (cols wc*128..+128)
    const int r0 = blockIdx.x * 128;
    const int b = blockIdx.x >> 3;

    if (tid < 128) s_sc[tid] = 0.f;

    // per-thread A source: row = r0 + (tid>>6)*16 + (tid&15), k-group g=(tid>>4)&3
    const size_t asrc = (size_t)(r0 + (tid >> 6) * 16 + (tid & 15)) * 512 + ((tid >> 4) & 3) * 8;

    f32x4 acc[4][8];
#pragma unroll
    for (int i = 0; i < 4; ++i)
#pragma unroll
        for (int j = 0; j < 8; ++j) acc[i][j] = (f32x4){0.f, 0.f, 0.f, 0.f};

#define STAGE_B(ktv, buf)                                                              \
    {                                                                                  \
        _Pragma("unroll")                                                              \
        for (int j = 0; j < 4; ++j) {                                                  \
            int c = w * 4 + j;                                                         \
            const unsigned short* gsrc = WaB + (size_t)(c * 16 + (ktv)) * 512 + l * 8; \
            unsigned short* ldst = &Bs[buf][c * 512 + l * 8];                          \
            __builtin_amdgcn_global_load_lds(                                          \
                (const __attribute__((address_space(1))) unsigned int*)gsrc,           \
                (__attribute__((address_space(3))) unsigned int*)ldst, 16, 0, 0);      \
        }                                                                              \
    }

#define CVT_WRITE_A(buf, f0, f1)                                                       \
    {                                                                                  \
        u16x8 p;                                                                       \
        p[0] = f2bf((f0).x); p[1] = f2bf((f0).y); p[2] = f2bf((f0).z); p[3] = f2bf((f0).w); \
        p[4] = f2bf((f1).x); p[5] = f2bf((f1).y); p[6] = f2bf((f1).z); p[7] = f2bf((f1).w); \
        *(u16x8*)&As[buf][tid * 8] = p;                                                \
    }

    // prologue: stage kt=0 into buffer 0
    {
        STAGE_B(0, 0);
        float4 f0 = *(const float4*)(ann + asrc);
        float4 f1 = *(const float4*)(ann + asrc + 4);
        CVT_WRITE_A(0, f0, f1);
    }
    __syncthreads();

    int cur = 0;
    for (int kt = 0; kt < 16; ++kt) {
        float4 f0n, f1n;
        const bool hasnext = (kt < 15);
        if (hasnext) {
            const float* src = ann + asrc + (kt + 1) * 32;
            f0n = *(const float4*)src;
            f1n = *(const float4*)(src + 4);
            STAGE_B(kt + 1, cur ^ 1);
        }
        // fragment reads (linear, conflict-free) + MFMA
        bf16x8 af[4];
#pragma unroll
        for (int tr = 0; tr < 4; ++tr)
            af[tr] = __builtin_bit_cast(bf16x8, *(const u16x8*)&As[cur][(wr * 4 + tr) * 512 + l * 8]);
#pragma unroll
        for (int tc = 0; tc < 8; ++tc) {
            bf16x8 bfv = __builtin_bit_cast(bf16x8, *(const u16x8*)&Bs[cur][(wc * 8 + tc) * 512 + l * 8]);
#pragma unroll
            for (int tr = 0; tr < 4; ++tr)
                acc[tr][tc] = __builtin_amdgcn_mfma_f32_16x16x32_bf16(af[tr], bfv, acc[tr][tc], 0, 0, 0);
        }
        if (hasnext) CVT_WRITE_A(cur ^ 1, f0n, f1n);
        __syncthreads();
        cur ^= 1;
    }
#undef STAGE_B
#undef CVT_WRITE_A

    // epilogue: rowsum of tanh(acc+q)*v
    float rsum[4][4];
#pragma unroll
    for (int i = 0; i < 4; ++i)
#pragma unroll
        for (int j = 0; j < 4; ++j) rsum[i][j] = 0.f;

#pragma unroll
    for (int tc = 0; tc < 8; ++tc) {
        int col = wc * 128 + tc * 16 + (l & 15);
        float qq = qv[b * 512 + col];
        float vv = v[col];
#pragma unroll
        for (int tr = 0; tr < 4; ++tr) {
            f32x4 a = acc[tr][tc];
#pragma unroll
            for (int r2 = 0; r2 < 4; ++r2)
                rsum[tr][r2] += tanh_fast(a[r2] + qq) * vv;
        }
    }
#pragma unroll
    for (int m = 1; m < 16; m <<= 1) {
#pragma unroll
        for (int tr = 0; tr < 4; ++tr)
#pragma unroll
            for (int r2 = 0; r2 < 4; ++r2)
                rsum[tr][r2] += __shfl_xor(rsum[tr][r2], m, 64);
    }
    if ((l & 15) == 0) {
        int g = l >> 4;
#pragma unroll
        for (int tr = 0; tr < 4; ++tr)
#pragma unroll
            for (int r2 = 0; r2 < 4; ++r2)
                atomicAdd(&s_sc[wr * 64 + tr * 16 + g * 4 + r2], rsum[tr][r2]);
    }
    __syncthreads();
    if (tid < 128) scores[r0 + tid] = s_sc[tid];
}

__global__ __launch_bounds__(256) void softmax_kernel(
    const float* __restrict__ scores, float* __restrict__ align_)
{
    const int b = blockIdx.x, tid = threadIdx.x;
    __shared__ float red[256];
    float s[4];
#pragma unroll
    for (int j = 0; j < 4; ++j) s[j] = scores[b * 1024 + j * 256 + tid];
    float mx = fmaxf(fmaxf(s[0], s[1]), fmaxf(s[2], s[3]));
    red[tid] = mx; __syncthreads();
    for (int off = 128; off > 0; off >>= 1) {
        if (tid < off) red[tid] = fmaxf(red[tid], red[tid + off]);
        __syncthreads();
    }
    mx = red[0]; __syncthreads();
    float e[4], sum = 0.f;
#pragma unroll
    for (int j = 0; j < 4; ++j) { e[j] = __expf(s[j] - mx); sum += e[j]; }
    red[tid] = sum; __syncthreads();
    for (int off = 128; off > 0; off >>= 1) {
        if (tid < off) red[tid] += red[tid + off];
        __syncthreads();
    }
    float inv = 1.0f / red[0];
#pragma unroll
    for (int j = 0; j < 4; ++j) align_[b * 1024 + j * 256 + tid] = e[j] * inv;
}

__global__ __launch_bounds__(256) void ctx_part_kernel(
    const float* __restrict__ ann, const float* __restrict__ align_,
    float* __restrict__ part)
{
    const int tid = threadIdx.x;
    const int b = blockIdx.y;
    const int d = blockIdx.x * 256 + tid;
    const int tc = blockIdx.z;
    __shared__ float al[256];
    al[tid] = align_[b * 1024 + tc * 256 + tid];
    __syncthreads();
    const float* ap = ann + ((size_t)(b * 1024 + tc * 256)) * 512 + d;
    float acc = 0.f;
#pragma unroll 4
    for (int tt = 0; tt < 256; ++tt) acc += al[tt] * ap[(size_t)tt * 512];
    part[(size_t)(tc * 64 + b) * 512 + d] = acc;
}

__global__ __launch_bounds__(256) void ctx_reduce_kernel(
    const float* __restrict__ part, float* __restrict__ ctx)
{
    int idx = blockIdx.x * 256 + threadIdx.x;  // < 32768
    ctx[idx] = part[idx] + part[32768 + idx] + part[65536 + idx] + part[98304 + idx];
}

extern "C" void kernel_launch(void* const* d_in, const int* in_sizes, int n_in,
                              void* d_out, int out_size, void* d_ws, size_t ws_size,
                              hipStream_t stream)
{
    (void)in_sizes; (void)n_in; (void)out_size; (void)ws_size;
    const float* memory    = (const float*)d_in[0];
    const float* context   = (const float*)d_in[1];
    const float* rnn_state = (const float*)d_in[2];
    const float* ann       = (const float*)d_in[3];
    const float* W_ih      = (const float*)d_in[4];
    const float* b_ih      = (const float*)d_in[5];
    const float* W_hh      = (const float*)d_in[6];
    const float* b_hh      = (const float*)d_in[7];
    const float* Wq        = (const float*)d_in[8];
    const float* bq        = (const float*)d_in[9];
    const float* Wa        = (const float*)d_in[10];
    const float* ba        = (const float*)d_in[11];
    const float* v         = (const float*)d_in[12];

    float* out    = (float*)d_out;
    float* h_new  = out;               // 32768
    float* ctx    = out + 32768;       // 32768
    float* align_ = out + 65536;       // 65536

    float* ws   = (float*)d_ws;
    float* gi   = ws;                  // 98304
    float* gh   = ws + 98304;          // 98304
    float* q    = ws + 196608;         // 32768
    float* sc   = ws + 229376;         // 65536
    float* part = ws + 294912;         // 131072
    unsigned short* WaB = (unsigned short*)((char*)d_ws + 1703936); // 512KB, fragment-major

    gru_gemm_kernel<<<dim3(24, 2), dim3(16, 16), 0, stream>>>(
        memory, context, rnn_state, W_ih, b_ih, W_hh, b_hh, gi, gh);
    waconv_kernel<<<dim3(128), dim3(256), 0, stream>>>(Wa, WaB);
    gru_elem_kernel<<<dim3(128), dim3(256), 0, stream>>>(gi, gh, rnn_state, h_new);
    pq_gemm_kernel<<<dim3(8), dim3(16, 16), 0, stream>>>(h_new, Wq, bq, ba, q);
    scores_kernel<<<dim3(512), dim3(512), 0, stream>>>(ann, WaB, q, v, sc);
    softmax_kernel<<<dim3(64), dim3(256), 0, stream>>>(sc, align_);
    ctx_part_kernel<<<dim3(2, 64, 4), dim3(256), 0, stream>>>(ann, align_, part);
    ctx_reduce_kernel<<<dim3(128), dim3(256), 0, stream>>>(part, ctx);
}

// Round 3
// 159.861 us; speedup vs baseline: 1.4879x; 1.2877x over previous
//
#include <hip/hip_runtime.h>
#include <hip/hip_bf16.h>

// B=64, T=1024, H=512, M=256
// outputs: h_new (64x512) | ctx (64x512) | align (64x1024), all fp32

typedef __attribute__((ext_vector_type(8))) __bf16 bf16x8;
typedef __attribute__((ext_vector_type(8))) unsigned short u16x8;
typedef __attribute__((ext_vector_type(4))) float f32x4;

__device__ __forceinline__ unsigned short f2bf(float f) {
    __hip_bfloat16 h = __float2bfloat16(f);
    return __builtin_bit_cast(unsigned short, h);
}
__device__ __forceinline__ float tanh_fast(float x) {
    float e = __expf(2.0f * x);
    return 1.0f - 2.0f / (e + 1.0f);   // safe at +/-inf
}
__device__ __forceinline__ float sigmoid_f(float x) {
    return 1.0f / (1.0f + __expf(-x));
}

// ---------------------------------------------------------------------------
// Fragment-major bf16 weight conversion for all 4 weight matrices.
// chunk cb local to matrix = NB*ktN + kt ; element:
// dst[cb*512 + l*8 + e] = bf16( src[(NB*16 + (l&15))*K + kt*32 + (l>>4)*8 + e] )
// Ranges: [0,2304) W_ih (N=1536,K=768,ktN=24); [2304,3840) W_hh (1536,512,16);
//         [3840,4352) Wq (512,512,16); [4352,4864) Wa (512,512,16)
__global__ __launch_bounds__(256) void wconv_kernel(
    const float* __restrict__ W_ih, const float* __restrict__ W_hh,
    const float* __restrict__ Wq, const float* __restrict__ Wa,
    unsigned short* __restrict__ WihB, unsigned short* __restrict__ WhhB,
    unsigned short* __restrict__ WqB, unsigned short* __restrict__ WaB)
{
    const int cb = blockIdx.x * 4 + (threadIdx.x >> 6);
    const int l = threadIdx.x & 63;
    const float* src;
    unsigned short* dst;
    int K, local, NB, kt;
    if (cb < 2304) {
        src = W_ih; dst = WihB; K = 768; local = cb;
        NB = local / 24; kt = local % 24;
    } else if (cb < 3840) {
        src = W_hh; dst = WhhB; K = 512; local = cb - 2304;
        NB = local >> 4; kt = local & 15;
    } else if (cb < 4352) {
        src = Wq; dst = WqB; K = 512; local = cb - 3840;
        NB = local >> 4; kt = local & 15;
    } else {
        src = Wa; dst = WaB; K = 512; local = cb - 4352;
        NB = local >> 4; kt = local & 15;
    }
    const float* s = src + (size_t)(NB * 16 + (l & 15)) * K + kt * 32 + (l >> 4) * 8;
    float4 f0 = *(const float4*)s;
    float4 f1 = *(const float4*)(s + 4);
    u16x8 p;
    p[0] = f2bf(f0.x); p[1] = f2bf(f0.y); p[2] = f2bf(f0.z); p[3] = f2bf(f0.w);
    p[4] = f2bf(f1.x); p[5] = f2bf(f1.y); p[6] = f2bf(f1.z); p[7] = f2bf(f1.w);
    *(u16x8*)&dst[(size_t)local * 512 + l * 8] = p;
}

// ---------------------------------------------------------------------------
// GRU step, fully fused: one wave per (16 batch rows x 16 h cols).
// gi = [memory|context] @ W_ih^T ; gh = rnn_state @ W_hh^T ; then elementwise.
__global__ __launch_bounds__(64) void gru_kernel(
    const float* __restrict__ memory, const float* __restrict__ context,
    const float* __restrict__ rnn_state,
    const unsigned short* __restrict__ WihB, const float* __restrict__ b_ih,
    const unsigned short* __restrict__ WhhB, const float* __restrict__ b_hh,
    float* __restrict__ h_new)
{
    const int l = threadIdx.x;
    const int mt = blockIdx.x >> 5;     // 0..3 batch tile
    const int hb = blockIdx.x & 31;     // 0..31 h col tile
    const int r = l & 15, g = l >> 4;
    const int row = mt * 16 + r;

    f32x4 a_ir = {0,0,0,0}, a_iz = {0,0,0,0}, a_in = {0,0,0,0};
    f32x4 a_hr = {0,0,0,0}, a_hz = {0,0,0,0}, a_hn = {0,0,0,0};

#define CVT8(f0, f1, AF)                                                           \
    {                                                                              \
        u16x8 p_;                                                                  \
        p_[0] = f2bf((f0).x); p_[1] = f2bf((f0).y); p_[2] = f2bf((f0).z); p_[3] = f2bf((f0).w); \
        p_[4] = f2bf((f1).x); p_[5] = f2bf((f1).y); p_[6] = f2bf((f1).z); p_[7] = f2bf((f1).w); \
        AF = __builtin_bit_cast(bf16x8, p_);                                       \
    }

    // gi: kt 0..7 from memory (K offset kt*32), kt 8..23 from context
#pragma unroll
    for (int kt = 0; kt < 8; ++kt) {
        const float* s = memory + (size_t)row * 256 + kt * 32 + g * 8;
        float4 f0 = *(const float4*)s, f1 = *(const float4*)(s + 4);
        bf16x8 af; CVT8(f0, f1, af);
        bf16x8 b0 = __builtin_bit_cast(bf16x8, *(const u16x8*)&WihB[((size_t)(hb) * 24 + kt) * 512 + l * 8]);
        bf16x8 b1 = __builtin_bit_cast(bf16x8, *(const u16x8*)&WihB[((size_t)(32 + hb) * 24 + kt) * 512 + l * 8]);
        bf16x8 b2 = __builtin_bit_cast(bf16x8, *(const u16x8*)&WihB[((size_t)(64 + hb) * 24 + kt) * 512 + l * 8]);
        a_ir = __builtin_amdgcn_mfma_f32_16x16x32_bf16(af, b0, a_ir, 0, 0, 0);
        a_iz = __builtin_amdgcn_mfma_f32_16x16x32_bf16(af, b1, a_iz, 0, 0, 0);
        a_in = __builtin_amdgcn_mfma_f32_16x16x32_bf16(af, b2, a_in, 0, 0, 0);
    }
#pragma unroll
    for (int kt = 8; kt < 24; ++kt) {
        const float* s = context + (size_t)row * 512 + (kt - 8) * 32 + g * 8;
        float4 f0 = *(const float4*)s, f1 = *(const float4*)(s + 4);
        bf16x8 af; CVT8(f0, f1, af);
        bf16x8 b0 = __builtin_bit_cast(bf16x8, *(const u16x8*)&WihB[((size_t)(hb) * 24 + kt) * 512 + l * 8]);
        bf16x8 b1 = __builtin_bit_cast(bf16x8, *(const u16x8*)&WihB[((size_t)(32 + hb) * 24 + kt) * 512 + l * 8]);
        bf16x8 b2 = __builtin_bit_cast(bf16x8, *(const u16x8*)&WihB[((size_t)(64 + hb) * 24 + kt) * 512 + l * 8]);
        a_ir = __builtin_amdgcn_mfma_f32_16x16x32_bf16(af, b0, a_ir, 0, 0, 0);
        a_iz = __builtin_amdgcn_mfma_f32_16x16x32_bf16(af, b1, a_iz, 0, 0, 0);
        a_in = __builtin_amdgcn_mfma_f32_16x16x32_bf16(af, b2, a_in, 0, 0, 0);
    }
#pragma unroll
    for (int kt = 0; kt < 16; ++kt) {
        const float* s = rnn_state + (size_t)row * 512 + kt * 32 + g * 8;
        float4 f0 = *(const float4*)s, f1 = *(const float4*)(s + 4);
        bf16x8 af; CVT8(f0, f1, af);
        bf16x8 b0 = __builtin_bit_cast(bf16x8, *(const u16x8*)&WhhB[((size_t)(hb) * 16 + kt) * 512 + l * 8]);
        bf16x8 b1 = __builtin_bit_cast(bf16x8, *(const u16x8*)&WhhB[((size_t)(32 + hb) * 16 + kt) * 512 + l * 8]);
        bf16x8 b2 = __builtin_bit_cast(bf16x8, *(const u16x8*)&WhhB[((size_t)(64 + hb) * 16 + kt) * 512 + l * 8]);
        a_hr = __builtin_amdgcn_mfma_f32_16x16x32_bf16(af, b0, a_hr, 0, 0, 0);
        a_hz = __builtin_amdgcn_mfma_f32_16x16x32_bf16(af, b1, a_hz, 0, 0, 0);
        a_hn = __builtin_amdgcn_mfma_f32_16x16x32_bf16(af, b2, a_hn, 0, 0, 0);
    }
    const int c = hb * 16 + r;
    const float bir = b_ih[c], biz = b_ih[512 + c], bin = b_ih[1024 + c];
    const float bhr = b_hh[c], bhz = b_hh[512 + c], bhn = b_hh[1024 + c];
#pragma unroll
    for (int r2 = 0; r2 < 4; ++r2) {
        const int m = mt * 16 + g * 4 + r2;
        float rr = sigmoid_f(a_ir[r2] + bir + a_hr[r2] + bhr);
        float zz = sigmoid_f(a_iz[r2] + biz + a_hz[r2] + bhz);
        float nn = tanh_fast(a_in[r2] + bin + rr * (a_hn[r2] + bhn));
        float h0 = rnn_state[(size_t)m * 512 + c];
        h_new[(size_t)m * 512 + c] = (1.f - zz) * nn + zz * h0;
    }
}

// q = h_new @ Wq^T + bq + ba ; one wave per (16 rows x 16 cols)
__global__ __launch_bounds__(64) void pq_kernel(
    const float* __restrict__ h_new, const unsigned short* __restrict__ WqB,
    const float* __restrict__ bq, const float* __restrict__ ba,
    float* __restrict__ q)
{
    const int l = threadIdx.x;
    const int mt = blockIdx.x >> 5;
    const int hb = blockIdx.x & 31;
    const int r = l & 15, g = l >> 4;
    const int row = mt * 16 + r;
    f32x4 acc = {0,0,0,0};
#pragma unroll
    for (int kt = 0; kt < 16; ++kt) {
        const float* s = h_new + (size_t)row * 512 + kt * 32 + g * 8;
        float4 f0 = *(const float4*)s, f1 = *(const float4*)(s + 4);
        bf16x8 af; CVT8(f0, f1, af);
        bf16x8 b0 = __builtin_bit_cast(bf16x8, *(const u16x8*)&WqB[((size_t)hb * 16 + kt) * 512 + l * 8]);
        acc = __builtin_amdgcn_mfma_f32_16x16x32_bf16(af, b0, acc, 0, 0, 0);
    }
    const int c = hb * 16 + r;
    const float add = bq[c] + ba[c];
#pragma unroll
    for (int r2 = 0; r2 < 4; ++r2)
        q[(size_t)(mt * 16 + g * 4 + r2) * 512 + c] = acc[r2] + add;
}

// ---------------- fused scores kernel v3 ------------------------------------
// 512 thr (8 waves: 2 wave-rows x 4 wave-cols), 128 ann rows x 512 cols/block.
// A: direct global->reg fp32 loads + in-reg cvt (no LDS). B: LDS dbuf via
// global_load_lds. One barrier per K-step.
__global__ __launch_bounds__(512, 2) void scores_kernel(
    const float* __restrict__ ann, const unsigned short* __restrict__ WaB,
    const float* __restrict__ qv, const float* __restrict__ v,
    float* __restrict__ scores)
{
    __shared__ unsigned short Bs0[16384];   // 32 KB
    __shared__ unsigned short Bs1[16384];   // 32 KB
    __shared__ float s_sc[128];

    const int tid = threadIdx.x;
    const int l = tid & 63;
    const int w = tid >> 6;          // 0..7
    const int wr = w >> 2;           // wave-row 0..1  (rows wr*64..+64)
    const int wc = w & 3;            // wave-col 0..3  (cols wc*128..+128)
    const int r0 = blockIdx.x * 128;
    const int b = blockIdx.x >> 3;

    if (tid < 128) s_sc[tid] = 0.f;

    // A source base: row = r0 + wr*64 + tr*16 + (l&15), k-grp g = l>>4
    const float* abase = ann + (size_t)(r0 + wr * 64 + (l & 15)) * 512 + (l >> 4) * 8;

    f32x4 acc[4][8];
#pragma unroll
    for (int i = 0; i < 4; ++i)
#pragma unroll
        for (int j = 0; j < 8; ++j) acc[i][j] = (f32x4){0.f, 0.f, 0.f, 0.f};

#define STAGE_B(ktv, BSBUF)                                                            \
    {                                                                                  \
        _Pragma("unroll")                                                              \
        for (int j_ = 0; j_ < 4; ++j_) {                                               \
            int c_ = w * 4 + j_;                                                       \
            const unsigned short* gsrc = WaB + (size_t)(c_ * 16 + (ktv)) * 512 + l * 8;\
            unsigned short* ldst = &BSBUF[c_ * 512 + l * 8];                           \
            __builtin_amdgcn_global_load_lds(                                          \
                (const __attribute__((address_space(1))) unsigned int*)gsrc,           \
                (__attribute__((address_space(3))) unsigned int*)ldst, 16, 0, 0);      \
        }                                                                              \
    }

#define LOADA(ktv, AR)                                                                 \
    {                                                                                  \
        _Pragma("unroll")                                                              \
        for (int tr_ = 0; tr_ < 4; ++tr_) {                                            \
            const float* s_ = abase + tr_ * (16 * 512) + (ktv) * 32;                   \
            AR[tr_][0] = *(const float4*)s_;                                           \
            AR[tr_][1] = *(const float4*)(s_ + 4);                                     \
        }                                                                              \
    }

#define MFMA_BODY(BSBUF, AR)                                                           \
    {                                                                                  \
        bf16x8 af_[4];                                                                 \
        _Pragma("unroll")                                                              \
        for (int tr_ = 0; tr_ < 4; ++tr_) CVT8(AR[tr_][0], AR[tr_][1], af_[tr_]);      \
        _Pragma("unroll")                                                              \
        for (int tc_ = 0; tc_ < 8; ++tc_) {                                            \
            bf16x8 bfv_ = __builtin_bit_cast(bf16x8,                                   \
                *(const u16x8*)&BSBUF[(wc * 8 + tc_) * 512 + l * 8]);                  \
            _Pragma("unroll")                                                          \
            for (int tr_ = 0; tr_ < 4; ++tr_)                                          \
                acc[tr_][tc_] = __builtin_amdgcn_mfma_f32_16x16x32_bf16(               \
                    af_[tr_], bfv_, acc[tr_][tc_], 0, 0, 0);                           \
        }                                                                              \
    }

    float4 aE[4][2], aO[4][2];
    // prologue: stage kt=0, load A kt=0
    STAGE_B(0, Bs0);
    LOADA(0, aE);
    __syncthreads();

    for (int kt2 = 0; kt2 < 8; ++kt2) {
        const int ktA = kt2 * 2;
        // even body: compute kt=ktA from Bs0/aE, prefetch ktA+1 into Bs1/aO
        STAGE_B(ktA + 1, Bs1);
        LOADA(ktA + 1, aO);
        MFMA_BODY(Bs0, aE);
        __syncthreads();
        // odd body: compute kt=ktA+1 from Bs1/aO, prefetch ktA+2 into Bs0/aE
        if (kt2 < 7) {
            STAGE_B(ktA + 2, Bs0);
            LOADA(ktA + 2, aE);
        }
        MFMA_BODY(Bs1, aO);
        __syncthreads();
    }
#undef STAGE_B
#undef LOADA
#undef MFMA_BODY

    // epilogue: rowsum of tanh(acc+q)*v
    float rsum[4][4];
#pragma unroll
    for (int i = 0; i < 4; ++i)
#pragma unroll
        for (int j = 0; j < 4; ++j) rsum[i][j] = 0.f;

#pragma unroll
    for (int tc = 0; tc < 8; ++tc) {
        int col = wc * 128 + tc * 16 + (l & 15);
        float qq = qv[b * 512 + col];
        float vv = v[col];
#pragma unroll
        for (int tr = 0; tr < 4; ++tr) {
            f32x4 a = acc[tr][tc];
#pragma unroll
            for (int r2 = 0; r2 < 4; ++r2)
                rsum[tr][r2] += tanh_fast(a[r2] + qq) * vv;
        }
    }
#pragma unroll
    for (int m = 1; m < 16; m <<= 1) {
#pragma unroll
        for (int tr = 0; tr < 4; ++tr)
#pragma unroll
            for (int r2 = 0; r2 < 4; ++r2)
                rsum[tr][r2] += __shfl_xor(rsum[tr][r2], m, 64);
    }
    if ((l & 15) == 0) {
        int g = l >> 4;
#pragma unroll
        for (int tr = 0; tr < 4; ++tr)
#pragma unroll
            for (int r2 = 0; r2 < 4; ++r2)
                atomicAdd(&s_sc[wr * 64 + tr * 16 + g * 4 + r2], rsum[tr][r2]);
    }
    __syncthreads();
    if (tid < 128) scores[r0 + tid] = s_sc[tid];
}

__global__ __launch_bounds__(256) void softmax_kernel(
    const float* __restrict__ scores, float* __restrict__ align_)
{
    const int b = blockIdx.x, tid = threadIdx.x;
    __shared__ float red[256];
    float s[4];
#pragma unroll
    for (int j = 0; j < 4; ++j) s[j] = scores[b * 1024 + j * 256 + tid];
    float mx = fmaxf(fmaxf(s[0], s[1]), fmaxf(s[2], s[3]));
    red[tid] = mx; __syncthreads();
    for (int off = 128; off > 0; off >>= 1) {
        if (tid < off) red[tid] = fmaxf(red[tid], red[tid + off]);
        __syncthreads();
    }
    mx = red[0]; __syncthreads();
    float e[4], sum = 0.f;
#pragma unroll
    for (int j = 0; j < 4; ++j) { e[j] = __expf(s[j] - mx); sum += e[j]; }
    red[tid] = sum; __syncthreads();
    for (int off = 128; off > 0; off >>= 1) {
        if (tid < off) red[tid] += red[tid + off];
        __syncthreads();
    }
    float inv = 1.0f / red[0];
#pragma unroll
    for (int j = 0; j < 4; ++j) align_[b * 1024 + j * 256 + tid] = e[j] * inv;
}

// ctx partials: block (b, tc) covers 128 rows x 512 d, float4-vectorized
__global__ __launch_bounds__(256) void ctx_part_kernel(
    const float* __restrict__ ann, const float* __restrict__ align_,
    float* __restrict__ part)
{
    const int tid = threadIdx.x;
    const int b = blockIdx.x;      // 0..63
    const int tc = blockIdx.y;     // 0..7
    __shared__ float al[128];
    __shared__ float4 red[128];
    if (tid < 128) al[tid] = align_[b * 1024 + tc * 128 + tid];
    __syncthreads();
    const int rp = tid >> 7, d4 = (tid & 127) * 4;
    const float* ap = ann + ((size_t)(b * 1024 + tc * 128)) * 512 + d4;
    float4 acc = {0.f, 0.f, 0.f, 0.f};
    for (int tt = rp; tt < 128; tt += 2) {
        float4 x = *(const float4*)(ap + (size_t)tt * 512);
        float wv = al[tt];
        acc.x += wv * x.x; acc.y += wv * x.y; acc.z += wv * x.z; acc.w += wv * x.w;
    }
    if (rp == 1) red[tid & 127] = acc;
    __syncthreads();
    if (rp == 0) {
        float4 o = red[tid];
        o.x += acc.x; o.y += acc.y; o.z += acc.z; o.w += acc.w;
        *(float4*)&part[((size_t)(tc * 64 + b)) * 512 + d4] = o;
    }
}

__global__ __launch_bounds__(256) void ctx_reduce_kernel(
    const float* __restrict__ part, float* __restrict__ ctx)
{
    int i4 = (blockIdx.x * 256 + threadIdx.x) * 4;  // < 32768
    float4 s = {0.f, 0.f, 0.f, 0.f};
#pragma unroll
    for (int p = 0; p < 8; ++p) {
        float4 x = *(const float4*)&part[(size_t)p * 32768 + i4];
        s.x += x.x; s.y += x.y; s.z += x.z; s.w += x.w;
    }
    *(float4*)&ctx[i4] = s;
}

extern "C" void kernel_launch(void* const* d_in, const int* in_sizes, int n_in,
                              void* d_out, int out_size, void* d_ws, size_t ws_size,
                              hipStream_t stream)
{
    (void)in_sizes; (void)n_in; (void)out_size; (void)ws_size;
    const float* memory    = (const float*)d_in[0];
    const float* context   = (const float*)d_in[1];
    const float* rnn_state = (const float*)d_in[2];
    const float* ann       = (const float*)d_in[3];
    const float* W_ih      = (const float*)d_in[4];
    const float* b_ih      = (const float*)d_in[5];
    const float* W_hh      = (const float*)d_in[6];
    const float* b_hh      = (const float*)d_in[7];
    const float* Wq        = (const float*)d_in[8];
    const float* bq        = (const float*)d_in[9];
    const float* Wa        = (const float*)d_in[10];
    const float* ba        = (const float*)d_in[11];
    const float* v         = (const float*)d_in[12];

    float* out    = (float*)d_out;
    float* h_new  = out;               // 32768
    float* ctx    = out + 32768;       // 32768
    float* align_ = out + 65536;       // 65536

    char* wsb = (char*)d_ws;
    float* q    = (float*)(wsb + 0);          // 128 KB
    float* sc   = (float*)(wsb + 131072);     // 256 KB
    float* part = (float*)(wsb + 393216);     // 1 MB
    unsigned short* WihB = (unsigned short*)(wsb + 1441792);  // 2.25 MB
    unsigned short* WhhB = (unsigned short*)(wsb + 3801088);  // 1.5 MB
    unsigned short* WqB  = (unsigned short*)(wsb + 5373952);  // 0.5 MB
    unsigned short* WaB  = (unsigned short*)(wsb + 5898240);  // 0.5 MB

    wconv_kernel<<<dim3(1216), dim3(256), 0, stream>>>(
        W_ih, W_hh, Wq, Wa, WihB, WhhB, WqB, WaB);
    gru_kernel<<<dim3(128), dim3(64), 0, stream>>>(
        memory, context, rnn_state, WihB, b_ih, WhhB, b_hh, h_new);
    pq_kernel<<<dim3(128), dim3(64), 0, stream>>>(h_new, WqB, bq, ba, q);
    scores_kernel<<<dim3(512), dim3(512), 0, stream>>>(ann, WaB, q, v, sc);
    softmax_kernel<<<dim3(64), dim3(256), 0, stream>>>(sc, align_);
    ctx_part_kernel<<<dim3(64, 8), dim3(256), 0, stream>>>(ann, align_, part);
    ctx_reduce_kernel<<<dim3(32), dim3(256), 0, stream>>>(part, ctx);
}

// Round 4
// 110.009 us; speedup vs baseline: 2.1622x; 1.4532x over previous
//
#include <hip/hip_runtime.h>
#include <hip/hip_bf16.h>

// B=64, T=1024, H=512, M=256
// outputs: h_new (64x512) | ctx (64x512) | align (64x1024), all fp32

typedef __attribute__((ext_vector_type(8))) __bf16 bf16x8;
typedef __attribute__((ext_vector_type(8))) unsigned short u16x8;
typedef __attribute__((ext_vector_type(4))) float f32x4;

__device__ __forceinline__ unsigned short f2bf(float f) {
    __hip_bfloat16 h = __float2bfloat16(f);
    return __builtin_bit_cast(unsigned short, h);
}
__device__ __forceinline__ float tanh_fast(float x) {
    float e = __expf(2.0f * x);
    return 1.0f - 2.0f / (e + 1.0f);   // safe at +/-inf
}
__device__ __forceinline__ float sigmoid_f(float x) {
    return 1.0f / (1.0f + __expf(-x));
}
// LDS byte-address swizzle: XOR bank bits 4-6 with bits 8-10.
__device__ __forceinline__ int swz(int x) { return x ^ (((x >> 8) & 7) << 4); }

// ---------------------------------------------------------------------------
// Fragment-major bf16 weight conversion for all 4 weight matrices.
// dst[cb*512 + l*8 + e] = bf16( src[(NB*16 + (l&15))*K + kt*32 + (l>>4)*8 + e] )
// cb local = NB*ktN + kt.
__global__ __launch_bounds__(256) void wconv_kernel(
    const float* __restrict__ W_ih, const float* __restrict__ W_hh,
    const float* __restrict__ Wq, const float* __restrict__ Wa,
    unsigned short* __restrict__ WihB, unsigned short* __restrict__ WhhB,
    unsigned short* __restrict__ WqB, unsigned short* __restrict__ WaB)
{
    const int cb = blockIdx.x * 4 + (threadIdx.x >> 6);
    const int l = threadIdx.x & 63;
    const float* src;
    unsigned short* dst;
    int K, local, NB, kt;
    if (cb < 2304) {
        src = W_ih; dst = WihB; K = 768; local = cb;
        NB = local / 24; kt = local % 24;
    } else if (cb < 3840) {
        src = W_hh; dst = WhhB; K = 512; local = cb - 2304;
        NB = local >> 4; kt = local & 15;
    } else if (cb < 4352) {
        src = Wq; dst = WqB; K = 512; local = cb - 3840;
        NB = local >> 4; kt = local & 15;
    } else {
        src = Wa; dst = WaB; K = 512; local = cb - 4352;
        NB = local >> 4; kt = local & 15;
    }
    const float* s = src + (size_t)(NB * 16 + (l & 15)) * K + kt * 32 + (l >> 4) * 8;
    float4 f0 = *(const float4*)s;
    float4 f1 = *(const float4*)(s + 4);
    u16x8 p;
    p[0] = f2bf(f0.x); p[1] = f2bf(f0.y); p[2] = f2bf(f0.z); p[3] = f2bf(f0.w);
    p[4] = f2bf(f1.x); p[5] = f2bf(f1.y); p[6] = f2bf(f1.z); p[7] = f2bf(f1.w);
    *(u16x8*)&dst[(size_t)local * 512 + l * 8] = p;
}

#define CVT8(f0, f1, AF)                                                           \
    {                                                                              \
        u16x8 p_;                                                                  \
        p_[0] = f2bf((f0).x); p_[1] = f2bf((f0).y); p_[2] = f2bf((f0).z); p_[3] = f2bf((f0).w); \
        p_[4] = f2bf((f1).x); p_[5] = f2bf((f1).y); p_[6] = f2bf((f1).z); p_[7] = f2bf((f1).w); \
        AF = __builtin_bit_cast(bf16x8, p_);                                       \
    }

// ---------------------------------------------------------------------------
// GRU step, fully fused: one wave per (16 batch rows x 16 h cols).
__global__ __launch_bounds__(64) void gru_kernel(
    const float* __restrict__ memory, const float* __restrict__ context,
    const float* __restrict__ rnn_state,
    const unsigned short* __restrict__ WihB, const float* __restrict__ b_ih,
    const unsigned short* __restrict__ WhhB, const float* __restrict__ b_hh,
    float* __restrict__ h_new)
{
    const int l = threadIdx.x;
    const int mt = blockIdx.x >> 5;     // 0..3 batch tile
    const int hb = blockIdx.x & 31;     // 0..31 h col tile
    const int r = l & 15, g = l >> 4;
    const int row = mt * 16 + r;

    f32x4 a_ir = {0,0,0,0}, a_iz = {0,0,0,0}, a_in = {0,0,0,0};
    f32x4 a_hr = {0,0,0,0}, a_hz = {0,0,0,0}, a_hn = {0,0,0,0};

#pragma unroll
    for (int kt = 0; kt < 8; ++kt) {
        const float* s = memory + (size_t)row * 256 + kt * 32 + g * 8;
        float4 f0 = *(const float4*)s, f1 = *(const float4*)(s + 4);
        bf16x8 af; CVT8(f0, f1, af);
        bf16x8 b0 = __builtin_bit_cast(bf16x8, *(const u16x8*)&WihB[((size_t)(hb) * 24 + kt) * 512 + l * 8]);
        bf16x8 b1 = __builtin_bit_cast(bf16x8, *(const u16x8*)&WihB[((size_t)(32 + hb) * 24 + kt) * 512 + l * 8]);
        bf16x8 b2 = __builtin_bit_cast(bf16x8, *(const u16x8*)&WihB[((size_t)(64 + hb) * 24 + kt) * 512 + l * 8]);
        a_ir = __builtin_amdgcn_mfma_f32_16x16x32_bf16(af, b0, a_ir, 0, 0, 0);
        a_iz = __builtin_amdgcn_mfma_f32_16x16x32_bf16(af, b1, a_iz, 0, 0, 0);
        a_in = __builtin_amdgcn_mfma_f32_16x16x32_bf16(af, b2, a_in, 0, 0, 0);
    }
#pragma unroll
    for (int kt = 8; kt < 24; ++kt) {
        const float* s = context + (size_t)row * 512 + (kt - 8) * 32 + g * 8;
        float4 f0 = *(const float4*)s, f1 = *(const float4*)(s + 4);
        bf16x8 af; CVT8(f0, f1, af);
        bf16x8 b0 = __builtin_bit_cast(bf16x8, *(const u16x8*)&WihB[((size_t)(hb) * 24 + kt) * 512 + l * 8]);
        bf16x8 b1 = __builtin_bit_cast(bf16x8, *(const u16x8*)&WihB[((size_t)(32 + hb) * 24 + kt) * 512 + l * 8]);
        bf16x8 b2 = __builtin_bit_cast(bf16x8, *(const u16x8*)&WihB[((size_t)(64 + hb) * 24 + kt) * 512 + l * 8]);
        a_ir = __builtin_amdgcn_mfma_f32_16x16x32_bf16(af, b0, a_ir, 0, 0, 0);
        a_iz = __builtin_amdgcn_mfma_f32_16x16x32_bf16(af, b1, a_iz, 0, 0, 0);
        a_in = __builtin_amdgcn_mfma_f32_16x16x32_bf16(af, b2, a_in, 0, 0, 0);
    }
#pragma unroll
    for (int kt = 0; kt < 16; ++kt) {
        const float* s = rnn_state + (size_t)row * 512 + kt * 32 + g * 8;
        float4 f0 = *(const float4*)s, f1 = *(const float4*)(s + 4);
        bf16x8 af; CVT8(f0, f1, af);
        bf16x8 b0 = __builtin_bit_cast(bf16x8, *(const u16x8*)&WhhB[((size_t)(hb) * 16 + kt) * 512 + l * 8]);
        bf16x8 b1 = __builtin_bit_cast(bf16x8, *(const u16x8*)&WhhB[((size_t)(32 + hb) * 16 + kt) * 512 + l * 8]);
        bf16x8 b2 = __builtin_bit_cast(bf16x8, *(const u16x8*)&WhhB[((size_t)(64 + hb) * 16 + kt) * 512 + l * 8]);
        a_hr = __builtin_amdgcn_mfma_f32_16x16x32_bf16(af, b0, a_hr, 0, 0, 0);
        a_hz = __builtin_amdgcn_mfma_f32_16x16x32_bf16(af, b1, a_hz, 0, 0, 0);
        a_hn = __builtin_amdgcn_mfma_f32_16x16x32_bf16(af, b2, a_hn, 0, 0, 0);
    }
    const int c = hb * 16 + r;
    const float bir = b_ih[c], biz = b_ih[512 + c], bin = b_ih[1024 + c];
    const float bhr = b_hh[c], bhz = b_hh[512 + c], bhn = b_hh[1024 + c];
#pragma unroll
    for (int r2 = 0; r2 < 4; ++r2) {
        const int m = mt * 16 + g * 4 + r2;
        float rr = sigmoid_f(a_ir[r2] + bir + a_hr[r2] + bhr);
        float zz = sigmoid_f(a_iz[r2] + biz + a_hz[r2] + bhz);
        float nn = tanh_fast(a_in[r2] + bin + rr * (a_hn[r2] + bhn));
        float h0 = rnn_state[(size_t)m * 512 + c];
        h_new[(size_t)m * 512 + c] = (1.f - zz) * nn + zz * h0;
    }
}

// q = h_new @ Wq^T + bq + ba ; one wave per (16 rows x 16 cols)
__global__ __launch_bounds__(64) void pq_kernel(
    const float* __restrict__ h_new, const unsigned short* __restrict__ WqB,
    const float* __restrict__ bq, const float* __restrict__ ba,
    float* __restrict__ q)
{
    const int l = threadIdx.x;
    const int mt = blockIdx.x >> 5;
    const int hb = blockIdx.x & 31;
    const int r = l & 15, g = l >> 4;
    const int row = mt * 16 + r;
    f32x4 acc = {0,0,0,0};
#pragma unroll
    for (int kt = 0; kt < 16; ++kt) {
        const float* s = h_new + (size_t)row * 512 + kt * 32 + g * 8;
        float4 f0 = *(const float4*)s, f1 = *(const float4*)(s + 4);
        bf16x8 af; CVT8(f0, f1, af);
        bf16x8 b0 = __builtin_bit_cast(bf16x8, *(const u16x8*)&WqB[((size_t)hb * 16 + kt) * 512 + l * 8]);
        acc = __builtin_amdgcn_mfma_f32_16x16x32_bf16(af, b0, acc, 0, 0, 0);
    }
    const int c = hb * 16 + r;
    const float add = bq[c] + ba[c];
#pragma unroll
    for (int r2 = 0; r2 < 4; ++r2)
        q[(size_t)(mt * 16 + g * 4 + r2) * 512 + c] = acc[r2] + add;
}

// ---------------- fused scores kernel v4 ------------------------------------
// Block: 256 thr (4 waves), 64 ann rows x ALL 512 cols. A staged ONCE to LDS
// (bf16 fragment-major, XOR-swizzled); Wa streams L2->reg. NO barrier in the
// main loop -- waves run free, latency hidden by ILP+TLP.
__global__ __launch_bounds__(256, 2) void scores_kernel(
    const float* __restrict__ ann, const unsigned short* __restrict__ WaB,
    const float* __restrict__ qv, const float* __restrict__ v,
    float* __restrict__ scores)
{
    __shared__ unsigned short As[32768];   // 64 KB
    __shared__ float s_sc[64];
    const int tid = threadIdx.x;
    const int l = tid & 63;
    const int w = tid >> 6;               // wave 0..3 -> cols w*128..+128
    const int r0 = blockIdx.x * 64;
    const int b = blockIdx.x >> 4;

    if (tid < 64) s_sc[tid] = 0.f;

    // ---- stage A tile: 64 rows x 512 fp32 -> bf16 frag-major swizzled LDS
    // frag layout (logical): chunk (rt*16+kt) [0,64) x lane l x 8 bf16;
    // element: A[rt*16+(l&15)][kt*32+(l>>4)*8 + e]
#pragma unroll
    for (int p = 0; p < 16; ++p) {
        int cidx = tid + p * 256;          // [0,4096) 8-float chunks
        int row = cidx >> 6;               // 0..63
        int c8 = cidx & 63;
        int kt = c8 >> 2, g = c8 & 3;
        int rt = row >> 4, r15 = row & 15;
        const float* s = ann + (size_t)(r0 + row) * 512 + c8 * 8;
        float4 f0 = *(const float4*)s, f1 = *(const float4*)(s + 4);
        u16x8 pk;
        pk[0] = f2bf(f0.x); pk[1] = f2bf(f0.y); pk[2] = f2bf(f0.z); pk[3] = f2bf(f0.w);
        pk[4] = f2bf(f1.x); pk[5] = f2bf(f1.y); pk[6] = f2bf(f1.z); pk[7] = f2bf(f1.w);
        int logical = (((rt * 16 + kt) * 64) + g * 16 + r15) * 16;
        *(u16x8*)((char*)As + swz(logical)) = pk;
    }
    __syncthreads();

    f32x4 acc[4][8];
#pragma unroll
    for (int i = 0; i < 4; ++i)
#pragma unroll
        for (int j = 0; j < 8; ++j) acc[i][j] = (f32x4){0.f, 0.f, 0.f, 0.f};

#pragma unroll 2
    for (int kt = 0; kt < 16; ++kt) {
        u16x8 bv[8];
#pragma unroll
        for (int ct = 0; ct < 8; ++ct)
            bv[ct] = *(const u16x8*)(WaB + ((size_t)((w * 8 + ct) * 16 + kt)) * 512 + l * 8);
#pragma unroll
        for (int rt = 0; rt < 4; ++rt) {
            int logical = ((rt * 16 + kt) * 64 + l) * 16;
            bf16x8 af = __builtin_bit_cast(bf16x8, *(const u16x8*)((char*)As + swz(logical)));
#pragma unroll
            for (int ct = 0; ct < 8; ++ct)
                acc[rt][ct] = __builtin_amdgcn_mfma_f32_16x16x32_bf16(
                    af, __builtin_bit_cast(bf16x8, bv[ct]), acc[rt][ct], 0, 0, 0);
        }
    }

    // epilogue: rsum[rt][r2] = sum over this wave's 128 cols of v*tanh(acc+q)
    float rsum[4][4];
#pragma unroll
    for (int i = 0; i < 4; ++i)
#pragma unroll
        for (int j = 0; j < 4; ++j) rsum[i][j] = 0.f;

#pragma unroll
    for (int ct = 0; ct < 8; ++ct) {
        int col = w * 128 + ct * 16 + (l & 15);
        float qq = qv[b * 512 + col];
        float vv = v[col];
#pragma unroll
        for (int rt = 0; rt < 4; ++rt) {
            f32x4 a = acc[rt][ct];
#pragma unroll
            for (int r2 = 0; r2 < 4; ++r2)
                rsum[rt][r2] += tanh_fast(a[r2] + qq) * vv;
        }
    }
#pragma unroll
    for (int m = 1; m < 16; m <<= 1) {
#pragma unroll
        for (int rt = 0; rt < 4; ++rt)
#pragma unroll
            for (int r2 = 0; r2 < 4; ++r2)
                rsum[rt][r2] += __shfl_xor(rsum[rt][r2], m, 64);
    }
    if ((l & 15) == 0) {
        int g = l >> 4;
#pragma unroll
        for (int rt = 0; rt < 4; ++rt)
#pragma unroll
            for (int r2 = 0; r2 < 4; ++r2)
                atomicAdd(&s_sc[rt * 16 + g * 4 + r2], rsum[rt][r2]);
    }
    __syncthreads();
    if (tid < 64) scores[r0 + tid] = s_sc[tid];
}

__global__ __launch_bounds__(256) void softmax_kernel(
    const float* __restrict__ scores, float* __restrict__ align_)
{
    const int b = blockIdx.x, tid = threadIdx.x;
    __shared__ float red[256];
    float s[4];
#pragma unroll
    for (int j = 0; j < 4; ++j) s[j] = scores[b * 1024 + j * 256 + tid];
    float mx = fmaxf(fmaxf(s[0], s[1]), fmaxf(s[2], s[3]));
    red[tid] = mx; __syncthreads();
    for (int off = 128; off > 0; off >>= 1) {
        if (tid < off) red[tid] = fmaxf(red[tid], red[tid + off]);
        __syncthreads();
    }
    mx = red[0]; __syncthreads();
    float e[4], sum = 0.f;
#pragma unroll
    for (int j = 0; j < 4; ++j) { e[j] = __expf(s[j] - mx); sum += e[j]; }
    red[tid] = sum; __syncthreads();
    for (int off = 128; off > 0; off >>= 1) {
        if (tid < off) red[tid] += red[tid + off];
        __syncthreads();
    }
    float inv = 1.0f / red[0];
#pragma unroll
    for (int j = 0; j < 4; ++j) align_[b * 1024 + j * 256 + tid] = e[j] * inv;
}

// ctx partials: block (b, tc) covers 128 rows x 512 d, float4-vectorized
__global__ __launch_bounds__(256) void ctx_part_kernel(
    const float* __restrict__ ann, const float* __restrict__ align_,
    float* __restrict__ part)
{
    const int tid = threadIdx.x;
    const int b = blockIdx.x;      // 0..63
    const int tc = blockIdx.y;     // 0..7
    __shared__ float al[128];
    __shared__ float4 red[128];
    if (tid < 128) al[tid] = align_[b * 1024 + tc * 128 + tid];
    __syncthreads();
    const int rp = tid >> 7, d4 = (tid & 127) * 4;
    const float* ap = ann + ((size_t)(b * 1024 + tc * 128)) * 512 + d4;
    float4 acc = {0.f, 0.f, 0.f, 0.f};
    for (int tt = rp; tt < 128; tt += 2) {
        float4 x = *(const float4*)(ap + (size_t)tt * 512);
        float wv = al[tt];
        acc.x += wv * x.x; acc.y += wv * x.y; acc.z += wv * x.z; acc.w += wv * x.w;
    }
    if (rp == 1) red[tid & 127] = acc;
    __syncthreads();
    if (rp == 0) {
        float4 o = red[tid];
        o.x += acc.x; o.y += acc.y; o.z += acc.z; o.w += acc.w;
        *(float4*)&part[((size_t)(tc * 64 + b)) * 512 + d4] = o;
    }
}

__global__ __launch_bounds__(256) void ctx_reduce_kernel(
    const float* __restrict__ part, float* __restrict__ ctx)
{
    int i4 = (blockIdx.x * 256 + threadIdx.x) * 4;  // < 32768
    float4 s = {0.f, 0.f, 0.f, 0.f};
#pragma unroll
    for (int p = 0; p < 8; ++p) {
        float4 x = *(const float4*)&part[(size_t)p * 32768 + i4];
        s.x += x.x; s.y += x.y; s.z += x.z; s.w += x.w;
    }
    *(float4*)&ctx[i4] = s;
}

extern "C" void kernel_launch(void* const* d_in, const int* in_sizes, int n_in,
                              void* d_out, int out_size, void* d_ws, size_t ws_size,
                              hipStream_t stream)
{
    (void)in_sizes; (void)n_in; (void)out_size; (void)ws_size;
    const float* memory    = (const float*)d_in[0];
    const float* context   = (const float*)d_in[1];
    const float* rnn_state = (const float*)d_in[2];
    const float* ann       = (const float*)d_in[3];
    const float* W_ih      = (const float*)d_in[4];
    const float* b_ih      = (const float*)d_in[5];
    const float* W_hh      = (const float*)d_in[6];
    const float* b_hh      = (const float*)d_in[7];
    const float* Wq        = (const float*)d_in[8];
    const float* bq        = (const float*)d_in[9];
    const float* Wa        = (const float*)d_in[10];
    const float* ba        = (const float*)d_in[11];
    const float* v         = (const float*)d_in[12];

    float* out    = (float*)d_out;
    float* h_new  = out;               // 32768
    float* ctx    = out + 32768;       // 32768
    float* align_ = out + 65536;       // 65536

    char* wsb = (char*)d_ws;
    float* q    = (float*)(wsb + 0);          // 128 KB
    float* sc   = (float*)(wsb + 131072);     // 256 KB
    float* part = (float*)(wsb + 393216);     // 1 MB
    unsigned short* WihB = (unsigned short*)(wsb + 1441792);  // 2.25 MB
    unsigned short* WhhB = (unsigned short*)(wsb + 3801088);  // 1.5 MB
    unsigned short* WqB  = (unsigned short*)(wsb + 5373952);  // 0.5 MB
    unsigned short* WaB  = (unsigned short*)(wsb + 5898240);  // 0.5 MB

    wconv_kernel<<<dim3(1216), dim3(256), 0, stream>>>(
        W_ih, W_hh, Wq, Wa, WihB, WhhB, WqB, WaB);
    gru_kernel<<<dim3(128), dim3(64), 0, stream>>>(
        memory, context, rnn_state, WihB, b_ih, WhhB, b_hh, h_new);
    pq_kernel<<<dim3(128), dim3(64), 0, stream>>>(h_new, WqB, bq, ba, q);
    scores_kernel<<<dim3(1024), dim3(256), 0, stream>>>(ann, WaB, q, v, sc);
    softmax_kernel<<<dim3(64), dim3(256), 0, stream>>>(sc, align_);
    ctx_part_kernel<<<dim3(64, 8), dim3(256), 0, stream>>>(ann, align_, part);
    ctx_reduce_kernel<<<dim3(32), dim3(256), 0, stream>>>(part, ctx);
}